// Round 14
// baseline (390.482 us; speedup 1.0000x reference)
//
#include <hip/hip_runtime.h>
#include <math.h>

// Problem constants
#define B_   64
#define IC_  4096
#define NC_  16
#define D_   16
#define IPB  8     // i's per block (NI = 512 i-blocks)
#define CH_  4     // i's per double-buffered W chunk (2 chunks/block)
#define WROW 68    // u32 per W-LDS row: 64 data (128 f16) + 4 pad
#define XROW 36    // u32 per x-LDS batch row: 32 data (8 i x 4 u32) + 4 pad

typedef __fp16 half2v __attribute__((ext_vector_type(2)));

#if __has_builtin(__builtin_amdgcn_fdot2)
#define HAVE_FDOT2 1
#else
#define HAVE_FDOT2 0
#endif

// pack 2 fp32 -> half2 in a u32 (v_cvt_pkrtz_f32_f16, single instr)
__device__ inline unsigned pk16(float a, float b) {
    half2v h = __builtin_amdgcn_cvt_pkrtz(a, b);
    return __builtin_bit_cast(unsigned, h);
}

// d = dot(w_half2, x_half2) + c with fp32 accumulate (v_dot2_f32_f16)
__device__ inline float hdot2(unsigned w, unsigned x, float cacc) {
#if HAVE_FDOT2
    return __builtin_amdgcn_fdot2(__builtin_bit_cast(half2v, w),
                                  __builtin_bit_cast(half2v, x), cacc, false);
#else
    half2v hw = __builtin_bit_cast(half2v, w);
    half2v hx = __builtin_bit_cast(half2v, x);
    return cacc + (float)hw.x * (float)hx.x + (float)hw.y * (float)hx.y;
#endif
}

// Sum-rotate within 16-lane DPP rows (the j dimension) on the VALU pipe.
// row_ror:N = 0x120|N. After rors 8,4,2,1 every lane holds the full 16-sum.
// HW-verified correct in rounds 5-13.
template <int CTRL>
__device__ inline float ror_add(float v) {
    int r = __builtin_amdgcn_update_dpp(0, __float_as_int(v), CTRL, 0xf, 0xf, false);
    return v + __int_as_float(r);
}

// Pass kernel. Block = 512 thr (8 waves): j = tid&15, c = (tid>>4)&3 (d-quad),
// wv = tid>>6. Wave wv owns batches b0..b0+3 (b0 = bg*32 + wv*4). W staged to
// LDS as packed f16 (RTZ), double-buffered 4-i chunks (2 chunks, 3 barriers);
// x staged once as packed f16 (uniform broadcast reads). Logits collapse to
// osum . u_hat; softmax over j: 2 shfl_xor (c-reduce) + 4 DPP ror-adds.
// Partials written as f16 pairs. Grid = 2*NI blocks (4 blocks/CU).
__global__ __launch_bounds__(512, 6)
void caps_pass(const float* __restrict__ inp, const float* __restrict__ W,
               const float* __restrict__ osum, unsigned* __restrict__ partials,
               int use_osum)
{
    __shared__ unsigned wlds[2][CH_ * NC_ * WROW];  // 2 x 4352 u32 = 34816 B
    __shared__ unsigned xlds[32 * XROW];            // 1152 u32  =  4608 B

    const int tid = threadIdx.x;
    const int j   = tid & 15;
    const int c   = (tid >> 4) & 3;
    const int wv  = tid >> 6;

    // XCD-aware swizzle: both bg of an i-block land on the same XCD L2.
    const int n   = blockIdx.x;
    const int cpx = gridDim.x >> 3;
    const int wg  = (n & 7) * cpx + (n >> 3);
    const int ib  = wg >> 1;
    const int bg  = wg & 1;
    const int i0  = ib * IPB;
    const int b0  = bg * 32 + wv * 4;

    // ---- x stage: thread t<256 handles (b = t>>3, il = t&7): 8 f32 -> 4 u32 ----
    if (tid < 32 * IPB) {
        const int xb = tid >> 3, xil = tid & 7;
        const float4* src =
            (const float4*)inp + ((size_t)(bg * 32 + xb) * IC_ + i0 + xil) * 2;
        float4 xa = src[0], xbv = src[1];
        *(uint4*)&xlds[xb * XROW + xil * 4] =
            make_uint4(pk16(xa.x, xa.y), pk16(xa.z, xa.w),
                       pk16(xbv.x, xbv.y), pk16(xbv.z, xbv.w));
    }

    // ---- W stage: chunk = CH_*16 rows x 16 uint4. Thread t stages uint4 #t
    //      (row1 = t>>4 in 0..31) and #(t+512) (row2 = row1+32). col = d. ----
    const int r1 = tid >> 4;        // row 0..31 -> (il = r>>4, j = r&15)
    const int sd = tid & 15;        // d index
    const int j1 = r1 & 15, il1 = r1 >> 4;   // u1: il 0..1
    const int il2 = il1 + 2;                 // u2: il 2..3, same j
    const float4* Wf4 = (const float4*)W;
    // f4 index for (j, i, d) = ((j*IC + i)*16 + d)*2
    const size_t wb1 = ((size_t)j1 * IC_) * 32 + (size_t)sd * 2;
    float4 ga0, ga1, gb0, gb1;

    // prologue: chunk 0 (i0 + il1 / i0 + il2)
    {
        const size_t ia = wb1 + (size_t)(i0 + il1) * 32;
        const size_t ibx = wb1 + (size_t)(i0 + il2) * 32;
        ga0 = Wf4[ia];  ga1 = Wf4[ia + 1];
        gb0 = Wf4[ibx]; gb1 = Wf4[ibx + 1];
        *(uint4*)&wlds[0][(il1 * NC_ + j1) * WROW + sd * 4] =
            make_uint4(pk16(ga0.x, ga0.y), pk16(ga0.z, ga0.w),
                       pk16(ga1.x, ga1.y), pk16(ga1.z, ga1.w));
        *(uint4*)&wlds[0][(il2 * NC_ + j1) * WROW + sd * 4] =
            make_uint4(pk16(gb0.x, gb0.y), pk16(gb0.z, gb0.w),
                       pk16(gb1.x, gb1.y), pk16(gb1.z, gb1.w));
    }
    __syncthreads();

    // osum rows for my 4 batches (registers)
    float4 os[4];
    if (use_osum) {
#pragma unroll
        for (int bi = 0; bi < 4; ++bi)
            os[bi] = ((const float4*)osum)[((size_t)(b0 + bi) * 16 + j) * 4 + c];
    }

    float acc[4][4];
#pragma unroll
    for (int bi = 0; bi < 4; ++bi)
#pragma unroll
        for (int dl = 0; dl < 4; ++dl) acc[bi][dl] = 0.0f;

    const int nch = IPB / CH_;   // 2
    int cur = 0;
    for (int ch = 0; ch < nch; ++ch) {
        if (ch + 1 < nch) {  // prefetch next chunk's W (global -> regs)
            const size_t ia = wb1 + (size_t)(i0 + CH_ + il1) * 32;
            const size_t ibx = wb1 + (size_t)(i0 + CH_ + il2) * 32;
            ga0 = Wf4[ia];  ga1 = Wf4[ia + 1];
            gb0 = Wf4[ibx]; gb1 = Wf4[ibx + 1];
        }
#pragma unroll
        for (int il = 0; il < CH_; ++il) {
            const int ilg = ch * CH_ + il;
            // W c-chunk: 4 d-rows x 8 f16 = 16 u32 = 4 x ds_read_b128
            const unsigned* wr = &wlds[cur][(il * NC_ + j) * WROW + c * 16];
            uint4 q0 = *(const uint4*)&wr[0];
            uint4 q1 = *(const uint4*)&wr[4];
            uint4 q2 = *(const uint4*)&wr[8];
            uint4 q3 = *(const uint4*)&wr[12];

            // x for my 4 batches (uniform broadcast b128 reads)
            uint4 xh[4];
#pragma unroll
            for (int bi = 0; bi < 4; ++bi)
                xh[bi] = *(const uint4*)&xlds[(wv * 4 + bi) * XROW + ilg * 4];

            float uh[4][4];
#pragma unroll
            for (int dl = 0; dl < 4; ++dl) {
                uint4 qq = (dl == 0) ? q0 : (dl == 1) ? q1 : (dl == 2) ? q2 : q3;
#pragma unroll
                for (int bi = 0; bi < 4; ++bi) {
                    float r = hdot2(qq.x, xh[bi].x, 0.0f);
                    r = hdot2(qq.y, xh[bi].y, r);
                    r = hdot2(qq.z, xh[bi].z, r);
                    uh[bi][dl] = hdot2(qq.w, xh[bi].w, r);
                }
            }

            float cc[4];
            if (use_osum) {
                float pb[4];
#pragma unroll
                for (int bi = 0; bi < 4; ++bi) {
                    float t = os[bi].x * uh[bi][0];
                    t = fmaf(os[bi].y, uh[bi][1], t);
                    t = fmaf(os[bi].z, uh[bi][2], t);
                    t = fmaf(os[bi].w, uh[bi][3], t);
                    pb[bi] = t;
                }
#pragma unroll
                for (int bi = 0; bi < 4; ++bi) {  // reduce over d-quads (c bits)
                    pb[bi] += __shfl_xor(pb[bi], 16);
                    pb[bi] += __shfl_xor(pb[bi], 32);
                }
#pragma unroll
                for (int bi = 0; bi < 4; ++bi) {
                    float e  = __expf(pb[bi]);      // no max-sub: |logit| small
                    float sm = ror_add<0x128>(e);   // sum over j via DPP rors (VALU)
                    sm = ror_add<0x124>(sm);
                    sm = ror_add<0x122>(sm);
                    sm = ror_add<0x121>(sm);
                    cc[bi] = __fdividef(e, sm);
                }
            } else {
#pragma unroll
                for (int bi = 0; bi < 4; ++bi) cc[bi] = 0.0625f;
            }

#pragma unroll
            for (int bi = 0; bi < 4; ++bi)
#pragma unroll
                for (int dl = 0; dl < 4; ++dl)
                    acc[bi][dl] = fmaf(cc[bi], uh[bi][dl], acc[bi][dl]);
        }
        if (ch + 1 < nch) {  // convert + write prefetched W chunk to other buffer
            const int nb = cur ^ 1;
            *(uint4*)&wlds[nb][(il1 * NC_ + j1) * WROW + sd * 4] =
                make_uint4(pk16(ga0.x, ga0.y), pk16(ga0.z, ga0.w),
                           pk16(ga1.x, ga1.y), pk16(ga1.z, ga1.w));
            *(uint4*)&wlds[nb][(il2 * NC_ + j1) * WROW + sd * 4] =
                make_uint4(pk16(gb0.x, gb0.y), pk16(gb0.z, gb0.w),
                           pk16(gb1.x, gb1.y), pk16(gb1.z, gb1.w));
        }
        __syncthreads();
        cur ^= 1;
    }

    // partials[ib][b][j][d] as f16 pairs: 8 u32 per (b,j); b64 stores
#pragma unroll
    for (int bi = 0; bi < 4; ++bi) {
        unsigned lo = pk16(acc[bi][0], acc[bi][1]);
        unsigned hi = pk16(acc[bi][2], acc[bi][3]);
        *(uint2*)&partials[(size_t)ib * (B_ * NC_ * 8) +
                           ((size_t)(b0 + bi) * NC_ + j) * 8 + c * 2] =
            make_uint2(lo, hi);
    }
}

// Reduce over NI i-blocks (f16 partials) + squash. Grid = 1024 blocks (one per
// (b,j)), 256 thr = 64 ksplit x 4 d-quads; b64 loads, fp32 accumulate.
// mode 0: osum = out ; mode 1: osum += out ; mode 2: d_out = out
__global__ __launch_bounds__(256)
void caps_reduce(const unsigned* __restrict__ partials, float* __restrict__ osum,
                 float* __restrict__ outb, int NI, int mode)
{
    __shared__ float4 red[256];
    const int tid = threadIdx.x;
    const int q   = tid & 3;    // d-quad
    const int ks  = tid >> 2;   // 0..63
    const int bj  = blockIdx.x;

    float4 s = make_float4(0.f, 0.f, 0.f, 0.f);
    for (int ibk = ks; ibk < NI; ibk += 64) {
        uint2 v = *(const uint2*)&partials[(size_t)ibk * (B_ * NC_ * 8) +
                                           (size_t)bj * 8 + q * 2];
        half2v h0 = __builtin_bit_cast(half2v, v.x);
        half2v h1 = __builtin_bit_cast(half2v, v.y);
        s.x += (float)h0.x; s.y += (float)h0.y;
        s.z += (float)h1.x; s.w += (float)h1.y;
    }
    red[tid] = s;
    __syncthreads();
    if (tid < 64) {
        float4 a = red[tid], b = red[tid + 64], cc = red[tid + 128], d = red[tid + 192];
        s.x = a.x + b.x + cc.x + d.x; s.y = a.y + b.y + cc.y + d.y;
        s.z = a.z + b.z + cc.z + d.z; s.w = a.w + b.w + cc.w + d.w;
        red[tid] = s;
    }
    __syncthreads();
    if (tid < 4) {
        float4 t = red[tid];
#pragma unroll
        for (int kk = 1; kk < 16; ++kk) {
            float4 v = red[kk * 4 + tid];
            t.x += v.x; t.y += v.y; t.z += v.z; t.w += v.w;
        }
        float s2 = t.x * t.x + t.y * t.y + t.z * t.z + t.w * t.w;
        s2 += __shfl_xor(s2, 1);
        s2 += __shfl_xor(s2, 2);
        float scale = s2 / (1.0f + s2) * rsqrtf(s2 + 1e-7f);
        float4 o = make_float4(scale * t.x, scale * t.y, scale * t.z, scale * t.w);
        size_t fi = (size_t)bj * 4 + tid;
        if (mode == 0) ((float4*)osum)[fi] = o;
        else if (mode == 1) {
            float4 cu = ((float4*)osum)[fi];
            cu.x += o.x; cu.y += o.y; cu.z += o.z; cu.w += o.w;
            ((float4*)osum)[fi] = cu;
        } else ((float4*)outb)[fi] = o;
    }
}

extern "C" void kernel_launch(void* const* d_in, const int* in_sizes, int n_in,
                              void* d_out, int out_size, void* d_ws, size_t ws_size,
                              hipStream_t stream)
{
    const float* inp = (const float*)d_in[0];  // [64, 4096, 8]
    const float* W   = (const float*)d_in[1];  // [16, 4096, 16, 8]
    float* out  = (float*)d_out;               // [64, 16, 16]

    float*    osum     = (float*)d_ws;                      // 16 KB used
    unsigned* partials = (unsigned*)((char*)d_ws + 65536);  // NI*32KB = 16.8 MB

    const int NI = IC_ / IPB;      // 512
    dim3 grid(2 * NI);             // 1024 blocks -> 4 blocks/CU

    // iter 0: c uniform (softmax of zeros)
    caps_pass<<<grid, 512, 0, stream>>>(inp, W, osum, partials, 0);
    caps_reduce<<<1024, 256, 0, stream>>>(partials, osum, out, NI, 0);
    // iter 1: logits = out0 . u_hat
    caps_pass<<<grid, 512, 0, stream>>>(inp, W, osum, partials, 1);
    caps_reduce<<<1024, 256, 0, stream>>>(partials, osum, out, NI, 1);
    // iter 2: logits = (out0 + out1) . u_hat
    caps_pass<<<grid, 512, 0, stream>>>(inp, W, osum, partials, 1);
    caps_reduce<<<1024, 256, 0, stream>>>(partials, osum, out, NI, 2);
}

// Round 15
// 121.252 us; speedup vs baseline: 3.2204x; 3.2204x over previous
//
#include <hip/hip_runtime.h>
#include <math.h>

// Problem constants
#define B_   64
#define IC_  4096
#define NC_  16
#define D_   16
#define IPB  8     // i's per block (NI = 512 i-blocks)
#define CH_  2     // i's per double-buffered W chunk
#define WROW 68    // u32 per W-LDS row: 64 data (128 f16) + 4 pad
#define XROW 36    // u32 per x-LDS batch row: 32 data (8 i x 4 u32) + 4 pad

typedef __fp16 half2v __attribute__((ext_vector_type(2)));

#if __has_builtin(__builtin_amdgcn_fdot2)
#define HAVE_FDOT2 1
#else
#define HAVE_FDOT2 0
#endif

// pack 2 fp32 -> half2 in a u32 (v_cvt_pkrtz_f32_f16, single instr)
__device__ inline unsigned pk16(float a, float b) {
    half2v h = __builtin_amdgcn_cvt_pkrtz(a, b);
    return __builtin_bit_cast(unsigned, h);
}

// d = dot(w_half2, x_half2) + c with fp32 accumulate (v_dot2_f32_f16)
__device__ inline float hdot2(unsigned w, unsigned x, float cacc) {
#if HAVE_FDOT2
    return __builtin_amdgcn_fdot2(__builtin_bit_cast(half2v, w),
                                  __builtin_bit_cast(half2v, x), cacc, false);
#else
    half2v hw = __builtin_bit_cast(half2v, w);
    half2v hx = __builtin_bit_cast(half2v, x);
    return cacc + (float)hw.x * (float)hx.x + (float)hw.y * (float)hx.y;
#endif
}

// Sum-rotate within 16-lane DPP rows (the j dimension) on the VALU pipe.
// row_ror:N = 0x120|N. After rors 8,4,2,1 every lane holds the full 16-sum.
// HW-verified correct in rounds 5-13.
template <int CTRL>
__device__ inline float ror_add(float v) {
    int r = __builtin_amdgcn_update_dpp(0, __float_as_int(v), CTRL, 0xf, 0xf, false);
    return v + __int_as_float(r);
}

// Pass kernel (R10 body; IPB=8 + f16 partials for 4 blocks/CU, 32 waves/CU).
// Block = 512 thr (8 waves): j = tid&15, c = (tid>>4)&3 (d-quad), wv = tid>>6.
// Wave wv owns batches b0..b0+3 (b0 = bg*32 + wv*4). W staged to LDS as packed
// f16 (RTZ), double-buffered; x staged once as packed f16 (uniform broadcast
// reads). Logits collapse to osum . u_hat; softmax over j: 2 shfl_xor
// (c-reduce) + 4 DPP ror-adds (j-sum). Grid = 2*NI blocks.
__global__ __launch_bounds__(512, 4)
void caps_pass(const float* __restrict__ inp, const float* __restrict__ W,
               const float* __restrict__ osum, unsigned* __restrict__ partials,
               int use_osum)
{
    __shared__ unsigned wlds[2][CH_ * NC_ * WROW];  // 2 x 2176 u32 = 17408 B
    __shared__ unsigned xlds[32 * XROW];            // 1152 u32 = 4608 B

    const int tid = threadIdx.x;
    const int j   = tid & 15;
    const int c   = (tid >> 4) & 3;
    const int wv  = tid >> 6;

    // XCD-aware swizzle: both bg of an i-block land on the same XCD L2.
    const int n   = blockIdx.x;
    const int cpx = gridDim.x >> 3;
    const int wg  = (n & 7) * cpx + (n >> 3);
    const int ib  = wg >> 1;
    const int bg  = wg & 1;
    const int i0  = ib * IPB;
    const int b0  = bg * 32 + wv * 4;

    // ---- x stage: thread t<256 handles (b = t>>3, il = t&7): 8 f32 -> 4 u32 ----
    if (tid < 32 * IPB) {
        const int xb = tid >> 3, xil = tid & 7;
        const float4* src =
            (const float4*)inp + ((size_t)(bg * 32 + xb) * IC_ + i0 + xil) * 2;
        float4 xa = src[0], xbv = src[1];
        *(uint4*)&xlds[xb * XROW + xil * 4] =
            make_uint4(pk16(xa.x, xa.y), pk16(xa.z, xa.w),
                       pk16(xbv.x, xbv.y), pk16(xbv.z, xbv.w));
    }

    // ---- W stage: thread t handles (row = t>>4 = il*16+j, col4 = t&15):
    //      one d-row (8 floats) of W[j, i0+il] -> uint4 ----
    const int srow = tid >> 4;   // il*16 + j  (il in 0..1)
    const int scol = tid & 15;   // d index
    const int sil  = srow >> 4;
    const int sj   = srow & 15;
    const float4* Wf4 = (const float4*)W;
    const size_t wgbase = ((size_t)sj * IC_) * 32 + scol * 2;  // + i*32

    float4 g0, g1;
    g0 = Wf4[wgbase + (size_t)(i0 + sil) * 32];
    g1 = Wf4[wgbase + (size_t)(i0 + sil) * 32 + 1];
    *(uint4*)&wlds[0][srow * WROW + scol * 4] =
        make_uint4(pk16(g0.x, g0.y), pk16(g0.z, g0.w),
                   pk16(g1.x, g1.y), pk16(g1.z, g1.w));
    __syncthreads();

    // osum rows for my 4 batches (registers)
    float4 os[4];
    if (use_osum) {
#pragma unroll
        for (int bi = 0; bi < 4; ++bi)
            os[bi] = ((const float4*)osum)[((size_t)(b0 + bi) * 16 + j) * 4 + c];
    }

    float acc[4][4];
#pragma unroll
    for (int bi = 0; bi < 4; ++bi)
#pragma unroll
        for (int dl = 0; dl < 4; ++dl) acc[bi][dl] = 0.0f;

    const int nch = IPB / CH_;   // 4
    int cur = 0;
    for (int ch = 0; ch < nch; ++ch) {
        if (ch + 1 < nch) {  // prefetch next chunk's W (global -> regs)
            const int inx = i0 + (ch + 1) * CH_ + sil;
            g0 = Wf4[wgbase + (size_t)inx * 32];
            g1 = Wf4[wgbase + (size_t)inx * 32 + 1];
        }
#pragma unroll
        for (int il = 0; il < CH_; ++il) {
            const int ilg = ch * CH_ + il;
            // W c-chunk: 4 d-rows x 8 f16 = 16 u32 = 4 x ds_read_b128
            const unsigned* wr = &wlds[cur][(il * NC_ + j) * WROW + c * 16];
            uint4 q0 = *(const uint4*)&wr[0];
            uint4 q1 = *(const uint4*)&wr[4];
            uint4 q2 = *(const uint4*)&wr[8];
            uint4 q3 = *(const uint4*)&wr[12];

            // x for my 4 batches (uniform broadcast b128 reads)
            uint4 xh[4];
#pragma unroll
            for (int bi = 0; bi < 4; ++bi)
                xh[bi] = *(const uint4*)&xlds[(wv * 4 + bi) * XROW + ilg * 4];

            float uh[4][4];
#pragma unroll
            for (int dl = 0; dl < 4; ++dl) {
                uint4 qq = (dl == 0) ? q0 : (dl == 1) ? q1 : (dl == 2) ? q2 : q3;
#pragma unroll
                for (int bi = 0; bi < 4; ++bi) {
                    float r = hdot2(qq.x, xh[bi].x, 0.0f);
                    r = hdot2(qq.y, xh[bi].y, r);
                    r = hdot2(qq.z, xh[bi].z, r);
                    uh[bi][dl] = hdot2(qq.w, xh[bi].w, r);
                }
            }

            float cc[4];
            if (use_osum) {
                float pb[4];
#pragma unroll
                for (int bi = 0; bi < 4; ++bi) {
                    float t = os[bi].x * uh[bi][0];
                    t = fmaf(os[bi].y, uh[bi][1], t);
                    t = fmaf(os[bi].z, uh[bi][2], t);
                    t = fmaf(os[bi].w, uh[bi][3], t);
                    pb[bi] = t;
                }
#pragma unroll
                for (int bi = 0; bi < 4; ++bi) {  // reduce over d-quads (c bits)
                    pb[bi] += __shfl_xor(pb[bi], 16);
                    pb[bi] += __shfl_xor(pb[bi], 32);
                }
#pragma unroll
                for (int bi = 0; bi < 4; ++bi) {
                    float e  = __expf(pb[bi]);      // no max-sub: |logit| small
                    float sm = ror_add<0x128>(e);   // sum over j via DPP rors (VALU)
                    sm = ror_add<0x124>(sm);
                    sm = ror_add<0x122>(sm);
                    sm = ror_add<0x121>(sm);
                    cc[bi] = __fdividef(e, sm);
                }
            } else {
#pragma unroll
                for (int bi = 0; bi < 4; ++bi) cc[bi] = 0.0625f;
            }

#pragma unroll
            for (int bi = 0; bi < 4; ++bi)
#pragma unroll
                for (int dl = 0; dl < 4; ++dl)
                    acc[bi][dl] = fmaf(cc[bi], uh[bi][dl], acc[bi][dl]);
        }
        if (ch + 1 < nch) {  // convert + write prefetched W chunk to other buffer
            const int nb = cur ^ 1;
            *(uint4*)&wlds[nb][srow * WROW + scol * 4] =
                make_uint4(pk16(g0.x, g0.y), pk16(g0.z, g0.w),
                           pk16(g1.x, g1.y), pk16(g1.z, g1.w));
        }
        __syncthreads();
        cur ^= 1;
    }

    // partials[ib][b][j][d] as f16 pairs: 8 u32 per (b,j); b64 stores
#pragma unroll
    for (int bi = 0; bi < 4; ++bi) {
        unsigned lo = pk16(acc[bi][0], acc[bi][1]);
        unsigned hi = pk16(acc[bi][2], acc[bi][3]);
        *(uint2*)&partials[(size_t)ib * (B_ * NC_ * 8) +
                           ((size_t)(b0 + bi) * NC_ + j) * 8 + c * 2] =
            make_uint2(lo, hi);
    }
}

// Reduce over NI i-blocks (f16 partials) + squash. Grid = 1024 blocks (one per
// (b,j)), 256 thr = 64 ksplit x 4 d-quads; b64 loads, fp32 accumulate.
// mode 0: osum = out ; mode 1: osum += out ; mode 2: d_out = out
__global__ __launch_bounds__(256)
void caps_reduce(const unsigned* __restrict__ partials, float* __restrict__ osum,
                 float* __restrict__ outb, int NI, int mode)
{
    __shared__ float4 red[256];
    const int tid = threadIdx.x;
    const int q   = tid & 3;    // d-quad
    const int ks  = tid >> 2;   // 0..63
    const int bj  = blockIdx.x;

    float4 s = make_float4(0.f, 0.f, 0.f, 0.f);
    for (int ibk = ks; ibk < NI; ibk += 64) {
        uint2 v = *(const uint2*)&partials[(size_t)ibk * (B_ * NC_ * 8) +
                                           (size_t)bj * 8 + q * 2];
        half2v h0 = __builtin_bit_cast(half2v, v.x);
        half2v h1 = __builtin_bit_cast(half2v, v.y);
        s.x += (float)h0.x; s.y += (float)h0.y;
        s.z += (float)h1.x; s.w += (float)h1.y;
    }
    red[tid] = s;
    __syncthreads();
    if (tid < 64) {
        float4 a = red[tid], b = red[tid + 64], cc = red[tid + 128], d = red[tid + 192];
        s.x = a.x + b.x + cc.x + d.x; s.y = a.y + b.y + cc.y + d.y;
        s.z = a.z + b.z + cc.z + d.z; s.w = a.w + b.w + cc.w + d.w;
        red[tid] = s;
    }
    __syncthreads();
    if (tid < 4) {
        float4 t = red[tid];
#pragma unroll
        for (int kk = 1; kk < 16; ++kk) {
            float4 v = red[kk * 4 + tid];
            t.x += v.x; t.y += v.y; t.z += v.z; t.w += v.w;
        }
        float s2 = t.x * t.x + t.y * t.y + t.z * t.z + t.w * t.w;
        s2 += __shfl_xor(s2, 1);
        s2 += __shfl_xor(s2, 2);
        float scale = s2 / (1.0f + s2) * rsqrtf(s2 + 1e-7f);
        float4 o = make_float4(scale * t.x, scale * t.y, scale * t.z, scale * t.w);
        size_t fi = (size_t)bj * 4 + tid;
        if (mode == 0) ((float4*)osum)[fi] = o;
        else if (mode == 1) {
            float4 cu = ((float4*)osum)[fi];
            cu.x += o.x; cu.y += o.y; cu.z += o.z; cu.w += o.w;
            ((float4*)osum)[fi] = cu;
        } else ((float4*)outb)[fi] = o;
    }
}

extern "C" void kernel_launch(void* const* d_in, const int* in_sizes, int n_in,
                              void* d_out, int out_size, void* d_ws, size_t ws_size,
                              hipStream_t stream)
{
    const float* inp = (const float*)d_in[0];  // [64, 4096, 8]
    const float* W   = (const float*)d_in[1];  // [16, 4096, 16, 8]
    float* out  = (float*)d_out;               // [64, 16, 16]

    float*    osum     = (float*)d_ws;                      // 16 KB used
    unsigned* partials = (unsigned*)((char*)d_ws + 65536);  // NI*32KB = 16.8 MB

    const int NI = IC_ / IPB;      // 512
    dim3 grid(2 * NI);             // 1024 blocks -> 4 blocks/CU, 32 waves/CU

    // iter 0: c uniform (softmax of zeros)
    caps_pass<<<grid, 512, 0, stream>>>(inp, W, osum, partials, 0);
    caps_reduce<<<1024, 256, 0, stream>>>(partials, osum, out, NI, 0);
    // iter 1: logits = out0 . u_hat
    caps_pass<<<grid, 512, 0, stream>>>(inp, W, osum, partials, 1);
    caps_reduce<<<1024, 256, 0, stream>>>(partials, osum, out, NI, 1);
    // iter 2: logits = (out0 + out1) . u_hat
    caps_pass<<<grid, 512, 0, stream>>>(inp, W, osum, partials, 1);
    caps_reduce<<<1024, 256, 0, stream>>>(partials, osum, out, NI, 2);
}

// Round 16
// 114.654 us; speedup vs baseline: 3.4057x; 1.0575x over previous
//
#include <hip/hip_runtime.h>
#include <math.h>

// Problem constants
#define B_   64
#define IC_  4096
#define NC_  16
#define D_   16
#define IPB  16    // i's per block (NI = 256 i-blocks)
#define CH_  2     // i's per double-buffered W chunk
#define WROW 68    // u32 per W-LDS row: 64 data (128 f16) + 4 pad
#define XROW 68    // u32 per x-LDS batch row: 64 data + 4 pad

typedef __fp16 half2v __attribute__((ext_vector_type(2)));

#if __has_builtin(__builtin_amdgcn_fdot2)
#define HAVE_FDOT2 1
#else
#define HAVE_FDOT2 0
#endif

// pack 2 fp32 -> half2 in a u32 (v_cvt_pkrtz_f32_f16, single instr)
__device__ inline unsigned pk16(float a, float b) {
    half2v h = __builtin_amdgcn_cvt_pkrtz(a, b);
    return __builtin_bit_cast(unsigned, h);
}

// d = dot(w_half2, x_half2) + c with fp32 accumulate (v_dot2_f32_f16)
__device__ inline float hdot2(unsigned w, unsigned x, float cacc) {
#if HAVE_FDOT2
    return __builtin_amdgcn_fdot2(__builtin_bit_cast(half2v, w),
                                  __builtin_bit_cast(half2v, x), cacc, false);
#else
    half2v hw = __builtin_bit_cast(half2v, w);
    half2v hx = __builtin_bit_cast(half2v, x);
    return cacc + (float)hw.x * (float)hx.x + (float)hw.y * (float)hx.y;
#endif
}

// Sum-rotate within 16-lane DPP rows (the j dimension) on the VALU pipe.
// row_ror:N = 0x120|N. After rors 8,4,2,1 every lane holds the full 16-sum.
// HW-verified correct in rounds 5-15.
template <int CTRL>
__device__ inline float ror_add(float v) {
    int r = __builtin_amdgcn_update_dpp(0, __float_as_int(v), CTRL, 0xf, 0xf, false);
    return v + __int_as_float(r);
}

// Pass kernel (R10 structure + f16 partials + exp2 softmax).
// Block = 512 thr (8 waves): j = tid&15, c = (tid>>4)&3 (d-quad), wv = tid>>6.
// Wave wv owns batches b0..b0+3 (b0 = bg*32 + wv*4). W staged to LDS as
// packed f16 (RTZ), double-buffered; x staged once as packed f16 (uniform
// broadcast reads). Logits collapse to osum . u_hat, computed in log2 domain
// (osum pre-scaled by log2(e) at load); softmax over j: 2 shfl_xor (c-reduce)
// + 4 DPP ror-adds. Grid = 2*NI blocks -> (bg in 0..1) x (NI i-blocks).
__global__ __launch_bounds__(512, 4)
void caps_pass(const float* __restrict__ inp, const float* __restrict__ W,
               const float* __restrict__ osum, unsigned* __restrict__ partials,
               int use_osum)
{
    __shared__ unsigned wlds[2][CH_ * NC_ * WROW];  // 2 x 2176 u32 = 17408 B
    __shared__ unsigned xlds[32 * XROW];            // 2176 u32 = 8704 B

    const int tid = threadIdx.x;
    const int j   = tid & 15;
    const int c   = (tid >> 4) & 3;
    const int wv  = tid >> 6;

    // XCD-aware swizzle: both bg of an i-block land on the same XCD L2.
    const int n   = blockIdx.x;
    const int cpx = gridDim.x >> 3;
    const int wg  = (n & 7) * cpx + (n >> 3);
    const int ib  = wg >> 1;
    const int bg  = wg & 1;
    const int i0  = ib * IPB;
    const int b0  = bg * 32 + wv * 4;

    // ---- x stage: thread t handles (b = t>>4, il = t&15): 8 f32 -> 4 u32 ----
    {
        const int xb = tid >> 4, xil = tid & 15;
        const float4* src =
            (const float4*)inp + ((size_t)(bg * 32 + xb) * IC_ + i0 + xil) * 2;
        float4 xa = src[0], xbv = src[1];
        *(uint4*)&xlds[xb * XROW + xil * 4] =
            make_uint4(pk16(xa.x, xa.y), pk16(xa.z, xa.w),
                       pk16(xbv.x, xbv.y), pk16(xbv.z, xbv.w));
    }

    // ---- W stage: thread t handles (row = t>>4 = il*16+j, col4 = t&15):
    //      one d-row (8 floats) of W[j, i0+il] -> uint4 ----
    const int srow = tid >> 4;   // il*16 + j
    const int scol = tid & 15;   // d index
    const int sil  = srow >> 4;
    const int sj   = srow & 15;
    const float4* Wf4 = (const float4*)W;
    const size_t wgbase = ((size_t)sj * IC_) * 32 + scol * 2;  // + i*32

    float4 g0, g1;
    g0 = Wf4[wgbase + (size_t)(i0 + sil) * 32];
    g1 = Wf4[wgbase + (size_t)(i0 + sil) * 32 + 1];
    *(uint4*)&wlds[0][srow * WROW + scol * 4] =
        make_uint4(pk16(g0.x, g0.y), pk16(g0.z, g0.w),
                   pk16(g1.x, g1.y), pk16(g1.z, g1.w));
    __syncthreads();

    // osum rows for my 4 batches, pre-scaled by log2(e) so the logit is
    // already in the base-2 domain (exp2 is the native v_exp_f32).
    float4 os[4];
    if (use_osum) {
#pragma unroll
        for (int bi = 0; bi < 4; ++bi) {
            float4 o = ((const float4*)osum)[((size_t)(b0 + bi) * 16 + j) * 4 + c];
            const float L2E = 1.44269504f;
            os[bi] = make_float4(o.x * L2E, o.y * L2E, o.z * L2E, o.w * L2E);
        }
    }

    float acc[4][4];
#pragma unroll
    for (int bi = 0; bi < 4; ++bi)
#pragma unroll
        for (int dl = 0; dl < 4; ++dl) acc[bi][dl] = 0.0f;

    const int nch = IPB / CH_;
    int cur = 0;
    for (int ch = 0; ch < nch; ++ch) {
        if (ch + 1 < nch) {  // prefetch next chunk's W (global -> regs)
            const int inx = i0 + (ch + 1) * CH_ + sil;
            g0 = Wf4[wgbase + (size_t)inx * 32];
            g1 = Wf4[wgbase + (size_t)inx * 32 + 1];
        }
#pragma unroll
        for (int il = 0; il < CH_; ++il) {
            const int ilg = ch * CH_ + il;
            // W c-chunk: 4 d-rows x 8 f16 = 16 u32 = 4 x ds_read_b128
            const unsigned* wr = &wlds[cur][(il * NC_ + j) * WROW + c * 16];
            uint4 q0 = *(const uint4*)&wr[0];
            uint4 q1 = *(const uint4*)&wr[4];
            uint4 q2 = *(const uint4*)&wr[8];
            uint4 q3 = *(const uint4*)&wr[12];

            // x for my 4 batches (uniform broadcast b128 reads)
            uint4 xh[4];
#pragma unroll
            for (int bi = 0; bi < 4; ++bi)
                xh[bi] = *(const uint4*)&xlds[(wv * 4 + bi) * XROW + ilg * 4];

            float uh[4][4];
#pragma unroll
            for (int dl = 0; dl < 4; ++dl) {
                uint4 qq = (dl == 0) ? q0 : (dl == 1) ? q1 : (dl == 2) ? q2 : q3;
#pragma unroll
                for (int bi = 0; bi < 4; ++bi) {
                    float r = hdot2(qq.x, xh[bi].x, 0.0f);
                    r = hdot2(qq.y, xh[bi].y, r);
                    r = hdot2(qq.z, xh[bi].z, r);
                    uh[bi][dl] = hdot2(qq.w, xh[bi].w, r);
                }
            }

            float cc[4];
            if (use_osum) {
                float pb[4];
#pragma unroll
                for (int bi = 0; bi < 4; ++bi) {
                    float t = os[bi].x * uh[bi][0];
                    t = fmaf(os[bi].y, uh[bi][1], t);
                    t = fmaf(os[bi].z, uh[bi][2], t);
                    t = fmaf(os[bi].w, uh[bi][3], t);
                    pb[bi] = t;
                }
#pragma unroll
                for (int bi = 0; bi < 4; ++bi) {  // reduce over d-quads (c bits)
                    pb[bi] += __shfl_xor(pb[bi], 16);
                    pb[bi] += __shfl_xor(pb[bi], 32);
                }
#pragma unroll
                for (int bi = 0; bi < 4; ++bi) {
                    float e  = exp2f(pb[bi]);       // native v_exp_f32 (2^x)
                    float sm = ror_add<0x128>(e);   // sum over j via DPP rors (VALU)
                    sm = ror_add<0x124>(sm);
                    sm = ror_add<0x122>(sm);
                    sm = ror_add<0x121>(sm);
                    cc[bi] = __fdividef(e, sm);
                }
            } else {
#pragma unroll
                for (int bi = 0; bi < 4; ++bi) cc[bi] = 0.0625f;
            }

#pragma unroll
            for (int bi = 0; bi < 4; ++bi)
#pragma unroll
                for (int dl = 0; dl < 4; ++dl)
                    acc[bi][dl] = fmaf(cc[bi], uh[bi][dl], acc[bi][dl]);
        }
        if (ch + 1 < nch) {  // convert + write prefetched W chunk to other buffer
            const int nb = cur ^ 1;
            *(uint4*)&wlds[nb][srow * WROW + scol * 4] =
                make_uint4(pk16(g0.x, g0.y), pk16(g0.z, g0.w),
                           pk16(g1.x, g1.y), pk16(g1.z, g1.w));
        }
        __syncthreads();
        cur ^= 1;
    }

    // partials[ib][b][j][d] as f16 pairs: 8 u32 per (b,j); b64 stores
#pragma unroll
    for (int bi = 0; bi < 4; ++bi) {
        unsigned lo = pk16(acc[bi][0], acc[bi][1]);
        unsigned hi = pk16(acc[bi][2], acc[bi][3]);
        *(uint2*)&partials[(size_t)ib * (B_ * NC_ * 8) +
                           ((size_t)(b0 + bi) * NC_ + j) * 8 + c * 2] =
            make_uint2(lo, hi);
    }
}

// Reduce over NI i-blocks (f16 partials) + squash. Grid = 1024 blocks (one per
// (b,j)), 256 thr = 64 ksplit x 4 d-quads; b64 loads, fp32 accumulate.
// mode 0: osum = out ; mode 1: osum += out ; mode 2: d_out = out
__global__ __launch_bounds__(256)
void caps_reduce(const unsigned* __restrict__ partials, float* __restrict__ osum,
                 float* __restrict__ outb, int NI, int mode)
{
    __shared__ float4 red[256];
    const int tid = threadIdx.x;
    const int q   = tid & 3;    // d-quad
    const int ks  = tid >> 2;   // 0..63
    const int bj  = blockIdx.x;

    float4 s = make_float4(0.f, 0.f, 0.f, 0.f);
    for (int ibk = ks; ibk < NI; ibk += 64) {
        uint2 v = *(const uint2*)&partials[(size_t)ibk * (B_ * NC_ * 8) +
                                           (size_t)bj * 8 + q * 2];
        half2v h0 = __builtin_bit_cast(half2v, v.x);
        half2v h1 = __builtin_bit_cast(half2v, v.y);
        s.x += (float)h0.x; s.y += (float)h0.y;
        s.z += (float)h1.x; s.w += (float)h1.y;
    }
    red[tid] = s;
    __syncthreads();
    if (tid < 64) {
        float4 a = red[tid], b = red[tid + 64], cc = red[tid + 128], d = red[tid + 192];
        s.x = a.x + b.x + cc.x + d.x; s.y = a.y + b.y + cc.y + d.y;
        s.z = a.z + b.z + cc.z + d.z; s.w = a.w + b.w + cc.w + d.w;
        red[tid] = s;
    }
    __syncthreads();
    if (tid < 4) {
        float4 t = red[tid];
#pragma unroll
        for (int kk = 1; kk < 16; ++kk) {
            float4 v = red[kk * 4 + tid];
            t.x += v.x; t.y += v.y; t.z += v.z; t.w += v.w;
        }
        float s2 = t.x * t.x + t.y * t.y + t.z * t.z + t.w * t.w;
        s2 += __shfl_xor(s2, 1);
        s2 += __shfl_xor(s2, 2);
        float scale = s2 / (1.0f + s2) * rsqrtf(s2 + 1e-7f);
        float4 o = make_float4(scale * t.x, scale * t.y, scale * t.z, scale * t.w);
        size_t fi = (size_t)bj * 4 + tid;
        if (mode == 0) ((float4*)osum)[fi] = o;
        else if (mode == 1) {
            float4 cu = ((float4*)osum)[fi];
            cu.x += o.x; cu.y += o.y; cu.z += o.z; cu.w += o.w;
            ((float4*)osum)[fi] = cu;
        } else ((float4*)outb)[fi] = o;
    }
}

extern "C" void kernel_launch(void* const* d_in, const int* in_sizes, int n_in,
                              void* d_out, int out_size, void* d_ws, size_t ws_size,
                              hipStream_t stream)
{
    const float* inp = (const float*)d_in[0];  // [64, 4096, 8]
    const float* W   = (const float*)d_in[1];  // [16, 4096, 16, 8]
    float* out  = (float*)d_out;               // [64, 16, 16]

    float*    osum     = (float*)d_ws;                      // 16 KB used
    unsigned* partials = (unsigned*)((char*)d_ws + 65536);  // NI*32KB = 8.4 MB

    const int NI = IC_ / IPB;      // 256
    dim3 grid(2 * NI);             // 512 blocks

    // iter 0: c uniform (softmax of zeros)
    caps_pass<<<grid, 512, 0, stream>>>(inp, W, osum, partials, 0);
    caps_reduce<<<1024, 256, 0, stream>>>(partials, osum, out, NI, 0);
    // iter 1: logits = out0 . u_hat
    caps_pass<<<grid, 512, 0, stream>>>(inp, W, osum, partials, 1);
    caps_reduce<<<1024, 256, 0, stream>>>(partials, osum, out, NI, 1);
    // iter 2: logits = (out0 + out1) . u_hat
    caps_pass<<<grid, 512, 0, stream>>>(inp, W, osum, partials, 1);
    caps_reduce<<<1024, 256, 0, stream>>>(partials, osum, out, NI, 2);
}